// Round 2
// baseline (382.137 us; speedup 1.0000x reference)
//
#include <hip/hip_runtime.h>
#include <hip/hip_fp16.h>

// QuantizedLinearWhisper: E2M1 block-32 fake-quant of x and W, then x_q @ W_q^T + bias.
// M=12000 (pad 12032=47*256), K=1280, N=5120. Outputs: out[12000][5120] f32, scale_w[5120][40] f32.
//
// R2: 256x256 8-phase-style GEMM (4 phases/tile, 2 tiles in LDS, counted vmcnt(8),
// raw s_barrier, setprio around MFMA clusters, 3-bit XOR LDS swizzle with
// pre-swizzled global source for global_load_lds). Quant kernels unchanged.

typedef _Float16 f16;
typedef _Float16 f16x8 __attribute__((ext_vector_type(8)));
typedef float f32x4 __attribute__((ext_vector_type(4)));

#define M_ROWS 12000
#define M_PAD  12032
#define N_COLS 5120
#define K_DIM  1280
#define KB     40
#define NT     20          // K tiles of 64
#define NTN    20          // N tiles of 256  (5120/256)

#define BAR() asm volatile("s_barrier" ::: "memory")

// ---- E2M1 nearest-level (strict > boundaries, identical to reference) ----
__device__ __forceinline__ float e2m1_level(float a) {
    float lv;
    if (a > 2.5f)       lv = (a > 3.5f) ? ((a > 5.0f) ? 6.0f : 4.0f) : 3.0f;
    else if (a > 1.25f) lv = (a > 1.75f) ? 2.0f : 1.5f;
    else                lv = (a > 0.75f) ? 1.0f : ((a > 0.25f) ? 0.5f : 0.0f);
    return lv;
}

__global__ __launch_bounds__(256) void quant_x_kernel(const float* __restrict__ x,
                                                      f16* __restrict__ xq) {
    int t = blockIdx.x * blockDim.x + threadIdx.x;
    int row = t / 160;
    int c8  = t % 160;
    f16x8 o;
    if (row < M_ROWS) {
        const float* p = x + (size_t)row * K_DIM + c8 * 8;
        float v[8];
        *(float4*)&v[0] = *(const float4*)p;
        *(float4*)&v[4] = *(const float4*)(p + 4);
        float am = 0.0f;
        #pragma unroll
        for (int i = 0; i < 8; ++i) am = fmaxf(am, fabsf(v[i]));
        am = fmaxf(am, __shfl_xor(am, 1));
        am = fmaxf(am, __shfl_xor(am, 2));
        float scale = fmaxf(am / 6.0f, 1e-12f);
        #pragma unroll
        for (int i = 0; i < 8; ++i) {
            float tq = v[i] / scale;
            float q  = copysignf(e2m1_level(fabsf(tq)), tq) * scale;
            o[i] = (f16)q;
        }
    } else {
        #pragma unroll
        for (int i = 0; i < 8; ++i) o[i] = (f16)0.0f;
    }
    *(f16x8*)(xq + (size_t)row * K_DIM + c8 * 8) = o;
}

__global__ __launch_bounds__(256) void quant_w_kernel(const float* __restrict__ w,
                                                      f16* __restrict__ wq,
                                                      float* __restrict__ scale_out) {
    int t = blockIdx.x * blockDim.x + threadIdx.x;
    int row = t / 160;
    int c8  = t % 160;
    const float* p = w + (size_t)row * K_DIM + c8 * 8;
    float v[8];
    *(float4*)&v[0] = *(const float4*)p;
    *(float4*)&v[4] = *(const float4*)(p + 4);
    float am = 0.0f;
    #pragma unroll
    for (int i = 0; i < 8; ++i) am = fmaxf(am, fabsf(v[i]));
    am = fmaxf(am, __shfl_xor(am, 1));
    am = fmaxf(am, __shfl_xor(am, 2));
    float scale = fmaxf(am / 6.0f, 1e-12f);
    if ((t & 3) == 0) scale_out[row * KB + (c8 >> 2)] = scale;
    f16x8 o;
    #pragma unroll
    for (int i = 0; i < 8; ++i) {
        float tq = v[i] / scale;
        float q  = copysignf(e2m1_level(fabsf(tq)), tq) * scale;
        o[i] = (f16)q;
    }
    *(f16x8*)(wq + (size_t)row * K_DIM + c8 * 8) = o;
}

// ---- GEMM 256x256, BK=64 ----
// LDS tile layout: [256 rows][8 chunks of 16B], chunk stored at (c ^ (r&7)).
// stage: global source pre-swizzled (permutation within the 128B row keeps coalescing),
// LDS dest linear in chunk index (global_load_lds requirement).
__device__ __forceinline__ void stage_mat(const f16* __restrict__ g, f16* l, int tid) {
    #pragma unroll
    for (int s = 0; s < 4; ++s) {
        int j = s * 512 + tid;          // chunk 0..2047
        int r = j >> 3;                 // tile row
        int c = (j & 7) ^ (r & 7);      // source k-chunk (inverse swizzle)
        __builtin_amdgcn_global_load_lds(
            (const __attribute__((address_space(1))) unsigned*)(g + (size_t)r * K_DIM + c * 8),
            (__attribute__((address_space(3))) unsigned*)(l + (size_t)j * 8), 16, 0, 0);
    }
}

template<bool STAGE, int VMN>
__device__ __forceinline__ void tile_body(f16* Ab, f16* Bb,
                                          const f16* gA, const f16* gB,
                                          f32x4 (&acc)[8][4],
                                          int tid, int arow, int brow, const int (&swz)[2]) {
    f16x8 aL[4][2], aH[4][2], bF[4][2];
    // ---- P1: read A m0-3 (both k-slices) + B all; MFMA m0-3 x n0-1
    #pragma unroll
    for (int fm = 0; fm < 4; ++fm) {
        aL[fm][0] = *(const f16x8*)&Ab[(arow + fm * 16) * 64 + swz[0]];
        aL[fm][1] = *(const f16x8*)&Ab[(arow + fm * 16) * 64 + swz[1]];
    }
    #pragma unroll
    for (int fn = 0; fn < 4; ++fn) {
        bF[fn][0] = *(const f16x8*)&Bb[(brow + fn * 16) * 64 + swz[0]];
        bF[fn][1] = *(const f16x8*)&Bb[(brow + fn * 16) * 64 + swz[1]];
    }
    BAR();
    __builtin_amdgcn_s_setprio(1);
    #pragma unroll
    for (int fm = 0; fm < 4; ++fm)
        #pragma unroll
        for (int fn = 0; fn < 2; ++fn) {
            acc[fm][fn] = __builtin_amdgcn_mfma_f32_16x16x32_f16(aL[fm][0], bF[fn][0], acc[fm][fn], 0, 0, 0);
            acc[fm][fn] = __builtin_amdgcn_mfma_f32_16x16x32_f16(aL[fm][1], bF[fn][1], acc[fm][fn], 0, 0, 0);
        }
    __builtin_amdgcn_s_setprio(0);
    BAR();
    // ---- P2: read A m4-7; MFMA m0-3 x n2-3; drain lgkm so buffer can be re-staged
    #pragma unroll
    for (int fm = 0; fm < 4; ++fm) {
        aH[fm][0] = *(const f16x8*)&Ab[(arow + 64 + fm * 16) * 64 + swz[0]];
        aH[fm][1] = *(const f16x8*)&Ab[(arow + 64 + fm * 16) * 64 + swz[1]];
    }
    BAR();
    __builtin_amdgcn_s_setprio(1);
    #pragma unroll
    for (int fm = 0; fm < 4; ++fm)
        #pragma unroll
        for (int fn = 2; fn < 4; ++fn) {
            acc[fm][fn] = __builtin_amdgcn_mfma_f32_16x16x32_f16(aL[fm][0], bF[fn][0], acc[fm][fn], 0, 0, 0);
            acc[fm][fn] = __builtin_amdgcn_mfma_f32_16x16x32_f16(aL[fm][1], bF[fn][1], acc[fm][fn], 0, 0, 0);
        }
    __builtin_amdgcn_s_setprio(0);
    asm volatile("s_waitcnt lgkmcnt(0)" ::: "memory");   // all reads of this buffer drained
    BAR();
    // ---- P3: stage A(t+2) into this A buffer; MFMA m4-7 x n0-1
    if (STAGE) stage_mat(gA, Ab, tid);
    BAR();
    __builtin_amdgcn_s_setprio(1);
    #pragma unroll
    for (int fm = 0; fm < 4; ++fm)
        #pragma unroll
        for (int fn = 0; fn < 2; ++fn) {
            acc[fm + 4][fn] = __builtin_amdgcn_mfma_f32_16x16x32_f16(aH[fm][0], bF[fn][0], acc[fm + 4][fn], 0, 0, 0);
            acc[fm + 4][fn] = __builtin_amdgcn_mfma_f32_16x16x32_f16(aH[fm][1], bF[fn][1], acc[fm + 4][fn], 0, 0, 0);
        }
    __builtin_amdgcn_s_setprio(0);
    BAR();
    // ---- P4: stage B(t+2); MFMA m4-7 x n2-3; counted vmcnt before barrier
    if (STAGE) stage_mat(gB, Bb, tid);
    BAR();
    __builtin_amdgcn_s_setprio(1);
    #pragma unroll
    for (int fm = 0; fm < 4; ++fm)
        #pragma unroll
        for (int fn = 2; fn < 4; ++fn) {
            acc[fm + 4][fn] = __builtin_amdgcn_mfma_f32_16x16x32_f16(aH[fm][0], bF[fn][0], acc[fm + 4][fn], 0, 0, 0);
            acc[fm + 4][fn] = __builtin_amdgcn_mfma_f32_16x16x32_f16(aH[fm][1], bF[fn][1], acc[fm + 4][fn], 0, 0, 0);
        }
    __builtin_amdgcn_s_setprio(0);
    if (VMN == 8)      asm volatile("s_waitcnt vmcnt(8)" ::: "memory");
    else if (VMN == 0) asm volatile("s_waitcnt vmcnt(0)" ::: "memory");
    BAR();
}

__global__ __launch_bounds__(512, 2) void gemm_kernel(const f16* __restrict__ A,
                                                      const f16* __restrict__ B,
                                                      const float* __restrict__ bias,
                                                      float* __restrict__ C) {
    extern __shared__ f16 sm[];            // 2 bufs x (A 16384 + B 16384) f16 = 128 KiB
    f16* A0 = sm;
    f16* B0 = sm + 16384;
    f16* A1 = sm + 32768;
    f16* B1 = sm + 49152;

    int mt = blockIdx.x / NTN;
    int nt = blockIdx.x % NTN;

    int tid  = threadIdx.x;
    int lane = tid & 63;
    int wid  = tid >> 6;
    int wr   = wid >> 2;                   // 0..1
    int wc   = wid & 3;                    // 0..3

    int arow = wr * 128 + (lane & 15);
    int brow = wc * 64 + (lane & 15);
    int swz[2] = { (((lane >> 4)    ) ^ (lane & 7)) * 8,
                   (((lane >> 4) + 4) ^ (lane & 7)) * 8 };

    const f16* gAb = A + (size_t)(mt * 256) * K_DIM;
    const f16* gBb = B + (size_t)(nt * 256) * K_DIM;

    f32x4 acc[8][4] = {};

    // prologue: stage tiles 0 and 1; wait tile 0 (8 of 16 loads)
    stage_mat(gAb,      A0, tid);
    stage_mat(gBb,      B0, tid);
    stage_mat(gAb + 64, A1, tid);
    stage_mat(gBb + 64, B1, tid);
    asm volatile("s_waitcnt vmcnt(8)" ::: "memory");
    BAR();

    #pragma unroll 2
    for (int t = 0; t < NT - 2; ++t) {
        f16* Ab = (t & 1) ? A1 : A0;
        f16* Bb = (t & 1) ? B1 : B0;
        tile_body<true, 8>(Ab, Bb, gAb + (t + 2) * 64, gBb + (t + 2) * 64,
                           acc, tid, arow, brow, swz);
    }
    tile_body<false, 0>(A0, B0, gAb, gBb, acc, tid, arow, brow, swz);   // t=18 (even)
    tile_body<false, -1>(A1, B1, gAb, gBb, acc, tid, arow, brow, swz);  // t=19

    // ---- epilogue: C = acc + bias.  C/D layout: col=lane&15, row=(lane>>4)*4+j
    int crow0 = mt * 256 + wr * 128;
    int ccol  = nt * 256 + wc * 64 + (lane & 15);
    float bz[4];
    #pragma unroll
    for (int fn = 0; fn < 4; ++fn) bz[fn] = bias[ccol + fn * 16];

    #pragma unroll
    for (int fm = 0; fm < 8; ++fm) {
        #pragma unroll
        for (int j = 0; j < 4; ++j) {
            int row = crow0 + fm * 16 + (lane >> 4) * 4 + j;
            if (row < M_ROWS) {
                float* cp = C + (size_t)row * N_COLS + ccol;
                #pragma unroll
                for (int fn = 0; fn < 4; ++fn)
                    cp[fn * 16] = acc[fm][fn][j] + bz[fn];
            }
        }
    }
}

extern "C" void kernel_launch(void* const* d_in, const int* in_sizes, int n_in,
                              void* d_out, int out_size, void* d_ws, size_t ws_size,
                              hipStream_t stream) {
    const float* x      = (const float*)d_in[0];
    const float* weight = (const float*)d_in[1];
    const float* bias   = (const float*)d_in[2];
    float* out     = (float*)d_out;
    float* scale_w = (float*)d_out + (size_t)M_ROWS * N_COLS;

    f16* xq = (f16*)d_ws;
    f16* wq = (f16*)((char*)d_ws + (size_t)M_PAD * K_DIM * sizeof(f16));

    (void)hipFuncSetAttribute((const void*)gemm_kernel,
                              hipFuncAttributeMaxDynamicSharedMemorySize, 131072);

    {
        int threads = M_PAD * (K_DIM / 8);
        quant_x_kernel<<<threads / 256, 256, 0, stream>>>(x, xq);
    }
    {
        int threads = N_COLS * (K_DIM / 8);
        quant_w_kernel<<<threads / 256, 256, 0, stream>>>(weight, wq, scale_w);
    }
    {
        int grid = (M_PAD / 256) * (N_COLS / 256);   // 47 * 20 = 940
        gemm_kernel<<<grid, 512, 131072, stream>>>(xq, wq, bias, out);
    }
}

// Round 3
// 211.174 us; speedup vs baseline: 1.8096x; 1.8096x over previous
//
#include <hip/hip_runtime.h>
#include <hip/hip_fp16.h>

// QuantizedLinearWhisper: E2M1 block-32 fake-quant of x and W, then x_q @ W_q^T + bias.
// M=12000 (pad 12032=47*256), K=1280, N=5120. Outputs: out[12000][5120] f32, scale_w[5120][40] f32.
//
// R3: 256x256 8-phase GEMM with per-phase fragment reads (<=12 ds_read/phase, <=64 frag
// regs live -> no spill), 2-tile LDS double buffer, counted vmcnt(8), raw s_barrier,
// setprio around MFMA, 3-bit XOR chunk swizzle (0 bank conflicts, proven R2).

typedef _Float16 f16;
typedef _Float16 f16x8 __attribute__((ext_vector_type(8)));
typedef float f32x4 __attribute__((ext_vector_type(4)));

#define M_ROWS 12000
#define M_PAD  12032
#define N_COLS 5120
#define K_DIM  1280
#define KB     40
#define NT     20          // K tiles of 64
#define NTN    20          // N tiles of 256

#define BAR()  asm volatile("s_barrier" ::: "memory")
#define LGKM0() asm volatile("s_waitcnt lgkmcnt(0)" ::: "memory")
#define GLDS(gp, lp) __builtin_amdgcn_global_load_lds( \
    (const __attribute__((address_space(1))) unsigned*)(gp), \
    (__attribute__((address_space(3))) unsigned*)(lp), 16, 0, 0)

// ---- E2M1 nearest-level (strict > boundaries, identical to reference) ----
__device__ __forceinline__ float e2m1_level(float a) {
    float lv;
    if (a > 2.5f)       lv = (a > 3.5f) ? ((a > 5.0f) ? 6.0f : 4.0f) : 3.0f;
    else if (a > 1.25f) lv = (a > 1.75f) ? 2.0f : 1.5f;
    else                lv = (a > 0.75f) ? 1.0f : ((a > 0.25f) ? 0.5f : 0.0f);
    return lv;
}

__global__ __launch_bounds__(256) void quant_x_kernel(const float* __restrict__ x,
                                                      f16* __restrict__ xq) {
    int t = blockIdx.x * blockDim.x + threadIdx.x;
    int row = t / 160;
    int c8  = t % 160;
    f16x8 o;
    if (row < M_ROWS) {
        const float* p = x + (size_t)row * K_DIM + c8 * 8;
        float v[8];
        *(float4*)&v[0] = *(const float4*)p;
        *(float4*)&v[4] = *(const float4*)(p + 4);
        float am = 0.0f;
        #pragma unroll
        for (int i = 0; i < 8; ++i) am = fmaxf(am, fabsf(v[i]));
        am = fmaxf(am, __shfl_xor(am, 1));
        am = fmaxf(am, __shfl_xor(am, 2));
        float scale = fmaxf(am / 6.0f, 1e-12f);
        #pragma unroll
        for (int i = 0; i < 8; ++i) {
            float tq = v[i] / scale;
            float q  = copysignf(e2m1_level(fabsf(tq)), tq) * scale;
            o[i] = (f16)q;
        }
    } else {
        #pragma unroll
        for (int i = 0; i < 8; ++i) o[i] = (f16)0.0f;
    }
    *(f16x8*)(xq + (size_t)row * K_DIM + c8 * 8) = o;
}

__global__ __launch_bounds__(256) void quant_w_kernel(const float* __restrict__ w,
                                                      f16* __restrict__ wq,
                                                      float* __restrict__ scale_out) {
    int t = blockIdx.x * blockDim.x + threadIdx.x;
    int row = t / 160;
    int c8  = t % 160;
    const float* p = w + (size_t)row * K_DIM + c8 * 8;
    float v[8];
    *(float4*)&v[0] = *(const float4*)p;
    *(float4*)&v[4] = *(const float4*)(p + 4);
    float am = 0.0f;
    #pragma unroll
    for (int i = 0; i < 8; ++i) am = fmaxf(am, fabsf(v[i]));
    am = fmaxf(am, __shfl_xor(am, 1));
    am = fmaxf(am, __shfl_xor(am, 2));
    float scale = fmaxf(am / 6.0f, 1e-12f);
    if ((t & 3) == 0) scale_out[row * KB + (c8 >> 2)] = scale;
    f16x8 o;
    #pragma unroll
    for (int i = 0; i < 8; ++i) {
        float tq = v[i] / scale;
        float q  = copysignf(e2m1_level(fabsf(tq)), tq) * scale;
        o[i] = (f16)q;
    }
    *(f16x8*)(wq + (size_t)row * K_DIM + c8 * 8) = o;
}

// ---- GEMM 256x256, BK=64, 512 threads (8 waves 2x4), per-wave 128x64 out ----
// LDS per buffer: A [256][8 chunks of 16B] (32KB) + B same (32KB); chunk c of row r
// stored at slot (c ^ (r&7)). Stage pre-swizzles the global source chunk.

__device__ __forceinline__ void stage_half(const f16* __restrict__ g, f16* l, int tid) {
    // 128 rows x 64 cols (16KB): 2 x global_load_lds(16B) per thread
    #pragma unroll
    for (int s = 0; s < 2; ++s) {
        int j = s * 512 + tid;          // chunk 0..1023
        int r = j >> 3;
        int c = (j & 7) ^ (r & 7);
        GLDS(g + (size_t)r * K_DIM + c * 8, l + (size_t)j * 8);
    }
}

// VMN: 8 = counted wait (main loop), 0 = full drain (t=18), -1 = none (t=19)
template<bool STAGE, int VMN>
__device__ __forceinline__ void tile_body(f16* Ab, f16* Bb,
                                          const f16* gA2, const f16* gB2,
                                          f32x4 (&acc)[8][4],
                                          int tid, int l15, const int (&swz)[2],
                                          int wr, int wc) {
    f16x8 a0[4][2], a1[4][2], b0[2][2], b1[2][2];
    const int arow0 = wr * 128 + l15;          // A quadrant 0 row base
    const int brow0 = wc * 64 + l15;           // B quadrant 0 row base

    // ---- P1: read A-q0 (8) + B-q0 (4); MFMA (m0-3, n0-1)
    #pragma unroll
    for (int fm = 0; fm < 4; ++fm) {
        a0[fm][0] = *(const f16x8*)&Ab[(arow0 + fm * 16) * 64 + swz[0]];
        a0[fm][1] = *(const f16x8*)&Ab[(arow0 + fm * 16) * 64 + swz[1]];
    }
    #pragma unroll
    for (int fn = 0; fn < 2; ++fn) {
        b0[fn][0] = *(const f16x8*)&Bb[(brow0 + fn * 16) * 64 + swz[0]];
        b0[fn][1] = *(const f16x8*)&Bb[(brow0 + fn * 16) * 64 + swz[1]];
    }
    BAR();
    LGKM0();
    __builtin_amdgcn_s_setprio(1);
    #pragma unroll
    for (int fm = 0; fm < 4; ++fm)
        #pragma unroll
        for (int fn = 0; fn < 2; ++fn) {
            acc[fm][fn] = __builtin_amdgcn_mfma_f32_16x16x32_f16(a0[fm][0], b0[fn][0], acc[fm][fn], 0, 0, 0);
            acc[fm][fn] = __builtin_amdgcn_mfma_f32_16x16x32_f16(a0[fm][1], b0[fn][1], acc[fm][fn], 0, 0, 0);
        }
    __builtin_amdgcn_s_setprio(0);
    BAR();

    // ---- P2: read B-q1 (4); MFMA (m0-3, n2-3)   [a0 still live, dies here]
    #pragma unroll
    for (int fn = 0; fn < 2; ++fn) {
        b1[fn][0] = *(const f16x8*)&Bb[(brow0 + 32 + fn * 16) * 64 + swz[0]];
        b1[fn][1] = *(const f16x8*)&Bb[(brow0 + 32 + fn * 16) * 64 + swz[1]];
    }
    BAR();
    LGKM0();
    __builtin_amdgcn_s_setprio(1);
    #pragma unroll
    for (int fm = 0; fm < 4; ++fm)
        #pragma unroll
        for (int fn = 0; fn < 2; ++fn) {
            acc[fm][fn + 2] = __builtin_amdgcn_mfma_f32_16x16x32_f16(a0[fm][0], b1[fn][0], acc[fm][fn + 2], 0, 0, 0);
            acc[fm][fn + 2] = __builtin_amdgcn_mfma_f32_16x16x32_f16(a0[fm][1], b1[fn][1], acc[fm][fn + 2], 0, 0, 0);
        }
    __builtin_amdgcn_s_setprio(0);
    BAR();

    // ---- P3: read A-q1 (8); stage B(t+2) (all B(t) reads drained by P2's lgkmcnt+barrier);
    //          MFMA (m4-7, n2-3)
    #pragma unroll
    for (int fm = 0; fm < 4; ++fm) {
        a1[fm][0] = *(const f16x8*)&Ab[(arow0 + 64 + fm * 16) * 64 + swz[0]];
        a1[fm][1] = *(const f16x8*)&Ab[(arow0 + 64 + fm * 16) * 64 + swz[1]];
    }
    if (STAGE) {
        stage_half(gB2, Bb, tid);
        stage_half(gB2 + 128 * K_DIM, Bb + 8192, tid);
    }
    BAR();
    LGKM0();
    __builtin_amdgcn_s_setprio(1);
    #pragma unroll
    for (int fm = 0; fm < 4; ++fm)
        #pragma unroll
        for (int fn = 0; fn < 2; ++fn) {
            acc[fm + 4][fn + 2] = __builtin_amdgcn_mfma_f32_16x16x32_f16(a1[fm][0], b1[fn][0], acc[fm + 4][fn + 2], 0, 0, 0);
            acc[fm + 4][fn + 2] = __builtin_amdgcn_mfma_f32_16x16x32_f16(a1[fm][1], b1[fn][1], acc[fm + 4][fn + 2], 0, 0, 0);
        }
    __builtin_amdgcn_s_setprio(0);
    BAR();

    // ---- P4: stage A(t+2) (all A(t) reads drained by P3's lgkmcnt+barrier);
    //          MFMA (m4-7, n0-1); counted vmcnt before closing barrier
    if (STAGE) {
        stage_half(gA2, Ab, tid);
        stage_half(gA2 + 128 * K_DIM, Ab + 8192, tid);
    }
    BAR();
    __builtin_amdgcn_s_setprio(1);
    #pragma unroll
    for (int fm = 0; fm < 4; ++fm)
        #pragma unroll
        for (int fn = 0; fn < 2; ++fn) {
            acc[fm + 4][fn] = __builtin_amdgcn_mfma_f32_16x16x32_f16(a1[fm][0], b0[fn][0], acc[fm + 4][fn], 0, 0, 0);
            acc[fm + 4][fn] = __builtin_amdgcn_mfma_f32_16x16x32_f16(a1[fm][1], b0[fn][1], acc[fm + 4][fn], 0, 0, 0);
        }
    __builtin_amdgcn_s_setprio(0);
    if (VMN == 8)      asm volatile("s_waitcnt vmcnt(8)" ::: "memory");
    else if (VMN == 0) asm volatile("s_waitcnt vmcnt(0)" ::: "memory");
    BAR();
}

__global__ __launch_bounds__(512, 2) void gemm_kernel(const f16* __restrict__ A,
                                                      const f16* __restrict__ B,
                                                      const float* __restrict__ bias,
                                                      float* __restrict__ C) {
    extern __shared__ f16 sm[];            // 2 bufs x (A 16384 + B 16384 f16) = 128 KiB
    int mt = blockIdx.x / NTN;
    int nt = blockIdx.x % NTN;

    int tid  = threadIdx.x;
    int lane = tid & 63;
    int wid  = tid >> 6;
    int wr   = wid >> 2;                   // 0..1
    int wc   = wid & 3;                    // 0..3
    int l15  = lane & 15;

    // chunk swizzle: row&7 == lane&7 for all fragment rows (row = 16*k + l15)
    int swz[2] = { (((lane >> 4)    ) ^ (lane & 7)) * 8,
                   (((lane >> 4) + 4) ^ (lane & 7)) * 8 };

    const f16* gAb = A + (size_t)(mt * 256) * K_DIM;
    const f16* gBb = B + (size_t)(nt * 256) * K_DIM;

    f16* A0 = sm;
    f16* B0 = sm + 16384;
    f16* A1 = sm + 32768;
    f16* B1 = sm + 49152;

    f32x4 acc[8][4] = {};

    // prologue: stage tiles 0 and 1 (16 loads/thread); wait for tile 0 (newest 8 in flight)
    stage_half(gAb,                A0, tid);
    stage_half(gAb + 128 * K_DIM,  A0 + 8192, tid);
    stage_half(gBb,                B0, tid);
    stage_half(gBb + 128 * K_DIM,  B0 + 8192, tid);
    stage_half(gAb + 64,               A1, tid);
    stage_half(gAb + 64 + 128 * K_DIM, A1 + 8192, tid);
    stage_half(gBb + 64,               B1, tid);
    stage_half(gBb + 64 + 128 * K_DIM, B1 + 8192, tid);
    asm volatile("s_waitcnt vmcnt(8)" ::: "memory");
    BAR();

    #pragma unroll 2
    for (int t = 0; t < NT - 2; ++t) {
        f16* Ab = (t & 1) ? A1 : A0;
        f16* Bb = (t & 1) ? B1 : B0;
        tile_body<true, 8>(Ab, Bb, gAb + (t + 2) * 64, gBb + (t + 2) * 64,
                           acc, tid, l15, swz, wr, wc);
    }
    tile_body<false, 0>(A0, B0, gAb, gBb, acc, tid, l15, swz, wr, wc);   // t=18
    tile_body<false, -1>(A1, B1, gAb, gBb, acc, tid, l15, swz, wr, wc);  // t=19

    // ---- epilogue: C = acc + bias.  C/D layout: col=lane&15, row=(lane>>4)*4+j
    int crow0 = mt * 256 + wr * 128;
    int ccol  = nt * 256 + wc * 64 + l15;
    float bz[4];
    #pragma unroll
    for (int fn = 0; fn < 4; ++fn) bz[fn] = bias[ccol + fn * 16];

    #pragma unroll
    for (int fm = 0; fm < 8; ++fm) {
        #pragma unroll
        for (int j = 0; j < 4; ++j) {
            int row = crow0 + fm * 16 + (lane >> 4) * 4 + j;
            if (row < M_ROWS) {
                float* cp = C + (size_t)row * N_COLS + ccol;
                #pragma unroll
                for (int fn = 0; fn < 4; ++fn)
                    cp[fn * 16] = acc[fm][fn][j] + bz[fn];
            }
        }
    }
}

extern "C" void kernel_launch(void* const* d_in, const int* in_sizes, int n_in,
                              void* d_out, int out_size, void* d_ws, size_t ws_size,
                              hipStream_t stream) {
    const float* x      = (const float*)d_in[0];
    const float* weight = (const float*)d_in[1];
    const float* bias   = (const float*)d_in[2];
    float* out     = (float*)d_out;
    float* scale_w = (float*)d_out + (size_t)M_ROWS * N_COLS;

    f16* xq = (f16*)d_ws;
    f16* wq = (f16*)((char*)d_ws + (size_t)M_PAD * K_DIM * sizeof(f16));

    (void)hipFuncSetAttribute((const void*)gemm_kernel,
                              hipFuncAttributeMaxDynamicSharedMemorySize, 131072);

    {
        int threads = M_PAD * (K_DIM / 8);
        quant_x_kernel<<<threads / 256, 256, 0, stream>>>(x, xq);
    }
    {
        int threads = N_COLS * (K_DIM / 8);
        quant_w_kernel<<<threads / 256, 256, 0, stream>>>(weight, wq, scale_w);
    }
    {
        int grid = (M_PAD / 256) * (N_COLS / 256);   // 47 * 20 = 940
        gemm_kernel<<<grid, 512, 131072, stream>>>(xq, wq, bias, out);
    }
}

// Round 4
// 209.798 us; speedup vs baseline: 1.8215x; 1.0066x over previous
//
#include <hip/hip_runtime.h>
#include <hip/hip_fp16.h>

// QuantizedLinearWhisper: E2M1 block-32 fake-quant of x and W, then x_q @ W_q^T + bias.
// M=12000 (pad 12032=47*256), K=1280, N=5120. Outputs: out[12000][5120] f32, scale_w[5120][40] f32.
//
// R4: same 256x256 double-buffered schedule as R3, but compiler-managed fine-grained
// lgkmcnt for fragment->MFMA deps (no forced full drain before MFMA clusters).
// Explicit lgkmcnt(0) only before the barriers that precede re-staging of the
// just-read LDS buffer (end of B-reads phase, end of A-reads phase). 7 barriers/tile.

typedef _Float16 f16;
typedef _Float16 f16x8 __attribute__((ext_vector_type(8)));
typedef float f32x4 __attribute__((ext_vector_type(4)));

#define M_ROWS 12000
#define M_PAD  12032
#define N_COLS 5120
#define K_DIM  1280
#define KB     40
#define NT     20          // K tiles of 64
#define NTN    20          // N tiles of 256

#define BAR()   asm volatile("s_barrier" ::: "memory")
#define LGKM0() asm volatile("s_waitcnt lgkmcnt(0)" ::: "memory")
#define GLDS(gp, lp) __builtin_amdgcn_global_load_lds( \
    (const __attribute__((address_space(1))) unsigned*)(gp), \
    (__attribute__((address_space(3))) unsigned*)(lp), 16, 0, 0)

// ---- E2M1 nearest-level (strict > boundaries, identical to reference) ----
__device__ __forceinline__ float e2m1_level(float a) {
    float lv;
    if (a > 2.5f)       lv = (a > 3.5f) ? ((a > 5.0f) ? 6.0f : 4.0f) : 3.0f;
    else if (a > 1.25f) lv = (a > 1.75f) ? 2.0f : 1.5f;
    else                lv = (a > 0.75f) ? 1.0f : ((a > 0.25f) ? 0.5f : 0.0f);
    return lv;
}

__global__ __launch_bounds__(256) void quant_x_kernel(const float* __restrict__ x,
                                                      f16* __restrict__ xq) {
    int t = blockIdx.x * blockDim.x + threadIdx.x;
    int row = t / 160;
    int c8  = t % 160;
    f16x8 o;
    if (row < M_ROWS) {
        const float* p = x + (size_t)row * K_DIM + c8 * 8;
        float v[8];
        *(float4*)&v[0] = *(const float4*)p;
        *(float4*)&v[4] = *(const float4*)(p + 4);
        float am = 0.0f;
        #pragma unroll
        for (int i = 0; i < 8; ++i) am = fmaxf(am, fabsf(v[i]));
        am = fmaxf(am, __shfl_xor(am, 1));
        am = fmaxf(am, __shfl_xor(am, 2));
        float scale = fmaxf(am / 6.0f, 1e-12f);
        #pragma unroll
        for (int i = 0; i < 8; ++i) {
            float tq = v[i] / scale;
            float q  = copysignf(e2m1_level(fabsf(tq)), tq) * scale;
            o[i] = (f16)q;
        }
    } else {
        #pragma unroll
        for (int i = 0; i < 8; ++i) o[i] = (f16)0.0f;
    }
    *(f16x8*)(xq + (size_t)row * K_DIM + c8 * 8) = o;
}

__global__ __launch_bounds__(256) void quant_w_kernel(const float* __restrict__ w,
                                                      f16* __restrict__ wq,
                                                      float* __restrict__ scale_out) {
    int t = blockIdx.x * blockDim.x + threadIdx.x;
    int row = t / 160;
    int c8  = t % 160;
    const float* p = w + (size_t)row * K_DIM + c8 * 8;
    float v[8];
    *(float4*)&v[0] = *(const float4*)p;
    *(float4*)&v[4] = *(const float4*)(p + 4);
    float am = 0.0f;
    #pragma unroll
    for (int i = 0; i < 8; ++i) am = fmaxf(am, fabsf(v[i]));
    am = fmaxf(am, __shfl_xor(am, 1));
    am = fmaxf(am, __shfl_xor(am, 2));
    float scale = fmaxf(am / 6.0f, 1e-12f);
    if ((t & 3) == 0) scale_out[row * KB + (c8 >> 2)] = scale;
    f16x8 o;
    #pragma unroll
    for (int i = 0; i < 8; ++i) {
        float tq = v[i] / scale;
        float q  = copysignf(e2m1_level(fabsf(tq)), tq) * scale;
        o[i] = (f16)q;
    }
    *(f16x8*)(wq + (size_t)row * K_DIM + c8 * 8) = o;
}

// ---- GEMM 256x256, BK=64, 512 threads (8 waves 2x4), per-wave 128x64 out ----
// LDS per buffer: A [256 rows][8 chunks of 16B] (32KB) + B same; chunk c of row r
// stored at slot (c ^ (r&7)); stage pre-swizzles the global source chunk.

__device__ __forceinline__ void stage_half(const f16* __restrict__ g, f16* l, int tid) {
    #pragma unroll
    for (int s = 0; s < 2; ++s) {
        int j = s * 512 + tid;          // chunk 0..1023
        int r = j >> 3;
        int c = (j & 7) ^ (r & 7);
        GLDS(g + (size_t)r * K_DIM + c * 8, l + (size_t)j * 8);
    }
}

// VMN: 8 = counted wait (main loop), 0 = full drain (t=NT-2), -1 = none (last)
template<bool STAGE, int VMN>
__device__ __forceinline__ void tile_body(f16* Ab, f16* Bb,
                                          const f16* gA2, const f16* gB2,
                                          f32x4 (&acc)[8][4],
                                          int tid, int l15, const int (&swz)[2],
                                          int wr, int wc) {
    f16x8 a0[4][2], a1[4][2], b0[2][2], b1[2][2];
    const int arow0 = wr * 128 + l15;
    const int brow0 = wc * 64 + l15;

    // ---- P1: read a0(8) + b0(4) + b1(4); MFMA (m0-3, n0-1)
    // (compiler inserts fine-grained lgkmcnt before each dependent MFMA)
    #pragma unroll
    for (int fm = 0; fm < 4; ++fm) {
        a0[fm][0] = *(const f16x8*)&Ab[(arow0 + fm * 16) * 64 + swz[0]];
        a0[fm][1] = *(const f16x8*)&Ab[(arow0 + fm * 16) * 64 + swz[1]];
    }
    #pragma unroll
    for (int fn = 0; fn < 2; ++fn) {
        b0[fn][0] = *(const f16x8*)&Bb[(brow0 + fn * 16) * 64 + swz[0]];
        b0[fn][1] = *(const f16x8*)&Bb[(brow0 + fn * 16) * 64 + swz[1]];
    }
    #pragma unroll
    for (int fn = 0; fn < 2; ++fn) {
        b1[fn][0] = *(const f16x8*)&Bb[(brow0 + 32 + fn * 16) * 64 + swz[0]];
        b1[fn][1] = *(const f16x8*)&Bb[(brow0 + 32 + fn * 16) * 64 + swz[1]];
    }
    BAR();
    __builtin_amdgcn_s_setprio(1);
    #pragma unroll
    for (int fm = 0; fm < 4; ++fm)
        #pragma unroll
        for (int fn = 0; fn < 2; ++fn) {
            acc[fm][fn] = __builtin_amdgcn_mfma_f32_16x16x32_f16(a0[fm][0], b0[fn][0], acc[fm][fn], 0, 0, 0);
            acc[fm][fn] = __builtin_amdgcn_mfma_f32_16x16x32_f16(a0[fm][1], b0[fn][1], acc[fm][fn], 0, 0, 0);
        }
    __builtin_amdgcn_s_setprio(0);
    BAR();

    // ---- P2: MFMA (m0-3, n2-3); no reads. End: all B reads of this buffer drained.
    __builtin_amdgcn_s_setprio(1);
    #pragma unroll
    for (int fm = 0; fm < 4; ++fm)
        #pragma unroll
        for (int fn = 0; fn < 2; ++fn) {
            acc[fm][fn + 2] = __builtin_amdgcn_mfma_f32_16x16x32_f16(a0[fm][0], b1[fn][0], acc[fm][fn + 2], 0, 0, 0);
            acc[fm][fn + 2] = __builtin_amdgcn_mfma_f32_16x16x32_f16(a0[fm][1], b1[fn][1], acc[fm][fn + 2], 0, 0, 0);
        }
    __builtin_amdgcn_s_setprio(0);
    LGKM0();                      // B-buffer reads drained -> safe to re-stage after BAR
    BAR();

    // ---- P3: read a1(8); stage B(t+2); MFMA (m4-7, n2-3).
    #pragma unroll
    for (int fm = 0; fm < 4; ++fm) {
        a1[fm][0] = *(const f16x8*)&Ab[(arow0 + 64 + fm * 16) * 64 + swz[0]];
        a1[fm][1] = *(const f16x8*)&Ab[(arow0 + 64 + fm * 16) * 64 + swz[1]];
    }
    if (STAGE) {
        stage_half(gB2, Bb, tid);
        stage_half(gB2 + 128 * K_DIM, Bb + 8192, tid);
    }
    BAR();
    __builtin_amdgcn_s_setprio(1);
    #pragma unroll
    for (int fm = 0; fm < 4; ++fm)
        #pragma unroll
        for (int fn = 0; fn < 2; ++fn) {
            acc[fm + 4][fn + 2] = __builtin_amdgcn_mfma_f32_16x16x32_f16(a1[fm][0], b1[fn][0], acc[fm + 4][fn + 2], 0, 0, 0);
            acc[fm + 4][fn + 2] = __builtin_amdgcn_mfma_f32_16x16x32_f16(a1[fm][1], b1[fn][1], acc[fm + 4][fn + 2], 0, 0, 0);
        }
    __builtin_amdgcn_s_setprio(0);
    LGKM0();                      // A-buffer reads drained -> safe to re-stage after BAR
    BAR();

    // ---- P4: stage A(t+2); MFMA (m4-7, n0-1); counted vmcnt before closing barrier
    if (STAGE) {
        stage_half(gA2, Ab, tid);
        stage_half(gA2 + 128 * K_DIM, Ab + 8192, tid);
    }
    BAR();
    __builtin_amdgcn_s_setprio(1);
    #pragma unroll
    for (int fm = 0; fm < 4; ++fm)
        #pragma unroll
        for (int fn = 0; fn < 2; ++fn) {
            acc[fm + 4][fn] = __builtin_amdgcn_mfma_f32_16x16x32_f16(a1[fm][0], b0[fn][0], acc[fm + 4][fn], 0, 0, 0);
            acc[fm + 4][fn] = __builtin_amdgcn_mfma_f32_16x16x32_f16(a1[fm][1], b0[fn][1], acc[fm + 4][fn], 0, 0, 0);
        }
    __builtin_amdgcn_s_setprio(0);
    if (VMN == 8)      asm volatile("s_waitcnt vmcnt(8)" ::: "memory");
    else if (VMN == 0) asm volatile("s_waitcnt vmcnt(0)" ::: "memory");
    BAR();
}

__global__ __launch_bounds__(512, 2) void gemm_kernel(const f16* __restrict__ A,
                                                      const f16* __restrict__ B,
                                                      const float* __restrict__ bias,
                                                      float* __restrict__ C) {
    extern __shared__ f16 sm[];            // 2 bufs x (A 16384 + B 16384 f16) = 128 KiB
    int mt = blockIdx.x / NTN;
    int nt = blockIdx.x % NTN;

    int tid  = threadIdx.x;
    int lane = tid & 63;
    int wid  = tid >> 6;
    int wr   = wid >> 2;                   // 0..1
    int wc   = wid & 3;                    // 0..3
    int l15  = lane & 15;

    int swz[2] = { (((lane >> 4)    ) ^ (lane & 7)) * 8,
                   (((lane >> 4) + 4) ^ (lane & 7)) * 8 };

    const f16* gAb = A + (size_t)(mt * 256) * K_DIM;
    const f16* gBb = B + (size_t)(nt * 256) * K_DIM;

    f16* A0 = sm;
    f16* B0 = sm + 16384;
    f16* A1 = sm + 32768;
    f16* B1 = sm + 49152;

    f32x4 acc[8][4] = {};

    // prologue: stage tiles 0 and 1 (16 loads/thread); wait for tile 0 (newest 8 remain)
    stage_half(gAb,                A0, tid);
    stage_half(gAb + 128 * K_DIM,  A0 + 8192, tid);
    stage_half(gBb,                B0, tid);
    stage_half(gBb + 128 * K_DIM,  B0 + 8192, tid);
    stage_half(gAb + 64,               A1, tid);
    stage_half(gAb + 64 + 128 * K_DIM, A1 + 8192, tid);
    stage_half(gBb + 64,               B1, tid);
    stage_half(gBb + 64 + 128 * K_DIM, B1 + 8192, tid);
    asm volatile("s_waitcnt vmcnt(8)" ::: "memory");
    BAR();

    #pragma unroll 2
    for (int t = 0; t < NT - 2; ++t) {
        f16* Ab = (t & 1) ? A1 : A0;
        f16* Bb = (t & 1) ? B1 : B0;
        tile_body<true, 8>(Ab, Bb, gAb + (t + 2) * 64, gBb + (t + 2) * 64,
                           acc, tid, l15, swz, wr, wc);
    }
    tile_body<false, 0>(A0, B0, gAb, gBb, acc, tid, l15, swz, wr, wc);   // t=18
    tile_body<false, -1>(A1, B1, gAb, gBb, acc, tid, l15, swz, wr, wc);  // t=19

    // ---- epilogue: C = acc + bias.  C/D layout: col=lane&15, row=(lane>>4)*4+j
    int crow0 = mt * 256 + wr * 128;
    int ccol  = nt * 256 + wc * 64 + l15;
    float bz[4];
    #pragma unroll
    for (int fn = 0; fn < 4; ++fn) bz[fn] = bias[ccol + fn * 16];

    #pragma unroll
    for (int fm = 0; fm < 8; ++fm) {
        #pragma unroll
        for (int j = 0; j < 4; ++j) {
            int row = crow0 + fm * 16 + (lane >> 4) * 4 + j;
            if (row < M_ROWS) {
                float* cp = C + (size_t)row * N_COLS + ccol;
                #pragma unroll
                for (int fn = 0; fn < 4; ++fn)
                    cp[fn * 16] = acc[fm][fn][j] + bz[fn];
            }
        }
    }
}

extern "C" void kernel_launch(void* const* d_in, const int* in_sizes, int n_in,
                              void* d_out, int out_size, void* d_ws, size_t ws_size,
                              hipStream_t stream) {
    const float* x      = (const float*)d_in[0];
    const float* weight = (const float*)d_in[1];
    const float* bias   = (const float*)d_in[2];
    float* out     = (float*)d_out;
    float* scale_w = (float*)d_out + (size_t)M_ROWS * N_COLS;

    f16* xq = (f16*)d_ws;
    f16* wq = (f16*)((char*)d_ws + (size_t)M_PAD * K_DIM * sizeof(f16));

    (void)hipFuncSetAttribute((const void*)gemm_kernel,
                              hipFuncAttributeMaxDynamicSharedMemorySize, 131072);

    {
        int threads = M_PAD * (K_DIM / 8);
        quant_x_kernel<<<threads / 256, 256, 0, stream>>>(x, xq);
    }
    {
        int threads = N_COLS * (K_DIM / 8);
        quant_w_kernel<<<threads / 256, 256, 0, stream>>>(weight, wq, scale_w);
    }
    {
        int grid = (M_PAD / 256) * (N_COLS / 256);   // 47 * 20 = 940
        gemm_kernel<<<grid, 512, 131072, stream>>>(xq, wq, bias, out);
    }
}